// Round 4
// baseline (95.668 us; speedup 1.0000x reference)
//
#include <hip/hip_runtime.h>

// Router: out[t] = x[t] @ W[split[t]] + b[split[t]]
// N=262144, D=128, E=8. fp32 in/out, bf16 MFMA.
// R4: NT=128/256-thread blocks -> 4 blocks/CU; ballot-based in-block
// bucketing (no atomics, no serial meta); per-wave 32-col slices.

typedef __bf16 bf16x8 __attribute__((ext_vector_type(8)));
typedef unsigned short u16x8 __attribute__((ext_vector_type(8)));
typedef float f32x4 __attribute__((ext_vector_type(4)));

__device__ __forceinline__ unsigned short f2bf(float f) {
    unsigned u = __builtin_bit_cast(unsigned, f);
    u += 0x7FFFu + ((u >> 16) & 1u);   // RNE
    return (unsigned short)(u >> 16);
}
__device__ __forceinline__ unsigned pack2(float a, float b) {
    return (unsigned)f2bf(a) | ((unsigned)f2bf(b) << 16);
}

// Transpose + convert W[e][f][g] (f32) -> Wt[e][g][f] (bf16).
__global__ void k_wt(const float* __restrict__ W, unsigned short* __restrict__ Wt) {
    __shared__ float T[16][132];
    int e = blockIdx.x >> 3;
    int g0 = (blockIdx.x & 7) << 4;
    const float* We = W + e * 128 * 128;
    #pragma unroll
    for (int i = 0; i < 2; ++i) {
        int idx = i * 256 + threadIdx.x;
        int f = idx >> 2, q = idx & 3;
        float4 v = *(const float4*)(We + f * 128 + g0 + q * 4);
        T[q * 4 + 0][f] = v.x; T[q * 4 + 1][f] = v.y;
        T[q * 4 + 2][f] = v.z; T[q * 4 + 3][f] = v.w;
    }
    __syncthreads();
    int g = threadIdx.x >> 4, fc = threadIdx.x & 15;
    u16x8 o;
    #pragma unroll
    for (int j = 0; j < 8; ++j) o[j] = f2bf(T[g][fc * 8 + j]);
    *(u16x8*)(Wt + ((e * 128 + g0 + g) * 128 + fc * 8)) = o;
}

#define NT 128     // tokens per block

__global__ __launch_bounds__(256, 4) void k_fused(
    const float* __restrict__ x, const int* __restrict__ split,
    const float* __restrict__ bias, const unsigned short* __restrict__ Wt,
    float* __restrict__ out) {

    // A-tile: NT rows x 128 bf16; 16B chunk fc of row s at ((fc^(s&7))*8).
    __shared__ unsigned short A[NT * 128];            // 32 KB
    __shared__ int wcnt[16];                          // [w][e], w=0,1
    __shared__ int startE[8], off1[8];
    __shared__ int dest[NT], trow[NT];
    __shared__ int exT[16], rbT[16], limT[16];
    __shared__ int Tn;

    const int tid = threadIdx.x;
    const int lane = tid & 63, w = tid >> 6;
    const long t0 = (long)blockIdx.x * NT;

    // phase A: issue streaming x loads (64 KB window, fully coalesced)
    float4 xv[16];
    const float* xb = x + t0 * 128;
    #pragma unroll
    for (int rr = 0; rr < 16; ++rr)
        xv[rr] = *(const float4*)(xb + (rr * 256 + tid) * 4);

    // ballot-based per-expert ranking (token waves are w=0,1)
    int e = 255, myrank = 0;
    if (tid < NT) e = split[t0 + tid];
    const unsigned long long below = (lane == 63) ? ~0ull >> 1 : (1ull << lane) - 1;
    #pragma unroll
    for (int ee = 0; ee < 8; ++ee) {
        unsigned long long m = __ballot(e == ee);
        if (e == ee) myrank = (int)__popcll(m & below);
        if (w < 2 && lane == ee) wcnt[w * 8 + ee] = (int)__popcll(m);
    }
    __syncthreads();

    // meta: wave 0, lanes 0..7 — scans via shuffles, parallel tile-list build
    if (w == 0 && lane < 8) {
        int c0 = wcnt[lane], c1 = wcnt[8 + lane];
        int cE = c0 + c1;
        int v = cE;
        #pragma unroll
        for (int d = 1; d < 8; d <<= 1) { int t2 = __shfl_up(v, d, 64); if (lane >= d) v += t2; }
        int sE = v - cE;
        startE[lane] = sE; off1[lane] = sE + c0;
        int nt = (cE + 15) >> 4;
        int u = nt;
        #pragma unroll
        for (int d = 1; d < 8; d <<= 1) { int t2 = __shfl_up(u, d, 64); if (lane >= d) u += t2; }
        int tb = u - nt;
        for (int k = 0; k < nt; ++k) {
            exT[tb + k] = lane; rbT[tb + k] = sE + k * 16;
            int rem = cE - k * 16; limT[tb + k] = rem < 16 ? rem : 16;
        }
        if (lane == 7) Tn = u;
    }
    __syncthreads();

    if (tid < NT) {
        int s = (w == 0 ? startE[e] : off1[e]) + myrank;  // bijective over [0,NT)
        dest[tid] = s;
        trow[s] = tid;
    }
    __syncthreads();

    // phase B: cvt f32->bf16, scatter rows into bucketed LDS order
    #pragma unroll
    for (int rr = 0; rr < 16; ++rr) {
        int c = rr * 256 + tid;
        int row = c >> 5;
        int s = dest[row];
        int fc = (c & 31) >> 1;
        int half = c & 1;
        unsigned d0 = pack2(xv[rr].x, xv[rr].y);
        unsigned d1 = pack2(xv[rr].z, xv[rr].w);
        *(uint2*)(A + s * 128 + ((fc ^ (s & 7)) << 3) + half * 4) = make_uint2(d0, d1);
    }
    __syncthreads();

    // phase C: wave w owns cols [w*32, w*32+32) — 2 col-blocks of 16
    const int l15 = lane & 15, lq = lane >> 4;
    const int T = Tn;

    bf16x8 bfrag[2][4];
    float bv[2];
    int preve = -1;

    for (int tau = 0; tau < T; ++tau) {
        int ee = exT[tau], rb = rbT[tau], lim = limT[tau];
        if (ee != preve) {
            preve = ee;
            #pragma unroll
            for (int j = 0; j < 2; ++j) {
                const unsigned short* Wb = Wt + ee * 16384 + (w * 32 + j * 16 + l15) * 128;
                #pragma unroll
                for (int kk = 0; kk < 4; ++kk)
                    bfrag[j][kk] = *(const bf16x8*)(Wb + (kk * 4 + lq) * 8);
                bv[j] = bias[ee * 128 + w * 32 + j * 16 + l15];
            }
        }
        int srow = rb + l15;
        srow = srow < NT ? srow : NT - 1;   // clamp; garbage rows masked at store
        f32x4 acc0 = {0.f, 0.f, 0.f, 0.f}, acc1 = {0.f, 0.f, 0.f, 0.f};
        #pragma unroll
        for (int kk = 0; kk < 4; ++kk) {
            int fc = kk * 4 + lq;
            bf16x8 a = *(const bf16x8*)(A + srow * 128 + ((fc ^ (srow & 7)) << 3));
            acc0 = __builtin_amdgcn_mfma_f32_16x16x32_bf16(a, bfrag[0][kk], acc0, 0, 0, 0);
            acc1 = __builtin_amdgcn_mfma_f32_16x16x32_bf16(a, bfrag[1][kk], acc1, 0, 0, 0);
        }
        // D layout: col = l15, row = lq*4+r
        #pragma unroll
        for (int r = 0; r < 4; ++r) {
            int ri = lq * 4 + r;
            if (ri < lim) {
                long o = (t0 + trow[rb + ri]) * 128 + w * 32 + l15;
                out[o]      = acc0[r] + bv[0];
                out[o + 16] = acc1[r] + bv[1];
            }
        }
    }
}

extern "C" void kernel_launch(void* const* d_in, const int* in_sizes, int n_in,
                              void* d_out, int out_size, void* d_ws, size_t ws_size,
                              hipStream_t stream) {
    const float* x     = (const float*)d_in[0];
    const int*   split = (const int*)d_in[1];
    const float* W     = (const float*)d_in[2];
    const float* bias  = (const float*)d_in[3];
    float* out = (float*)d_out;

    int n = in_sizes[1];                      // 262144
    unsigned short* Wt = (unsigned short*)d_ws;   // 8*128*128 bf16 = 256 KB

    k_wt<<<64, 256, 0, stream>>>(W, Wt);
    k_fused<<<n / NT, 256, 0, stream>>>(x, split, bias, Wt, out);
}